// Round 18
// baseline (50.687 us; speedup 1.0000x reference)
//
#include <hip/hip_runtime.h>
#include <hip/hip_cooperative_groups.h>

namespace cg = cooperative_groups;

// GD_lagrange_multi fused kernel for MI355X (gfx950).  Round 18: closed form
// (R17) split across the FULL chip via cooperative launch.
//   Om_N = (1+u)^N ⊙ Om_0  -  mu*ro * YpT @ [ S1*(M0 - T) + S2*Mu ]
//   M0 = Yp@Om_0,  Mu = Yp@(u⊙Om_0),  S1 = N(N-1)/2,  S2 = N(N-1)(N-2)/6,
//   u = -mu / ||Om_0 row||  (frozen norm; absmax bit-identical since R13).
// Grid = 256 blocks (1/CU, co-resident) x 512 threads; block = (wb, half):
// 8 waves, wave owns 64 g-rows = 4 MFMA tiles (16x16x16 f16, f32 accum).
//   Phase 1: load Yp[:,chunk] (b128) + Om chunk; uf; cOm = (1+u)^N*Om (regs);
//            partial W = S1*P0 + (S2/SIG)*Pu  -> block-reduce -> d_ws[bid].
//   grid.sync()  (cooperative; all blocks resident: 1 block/CU)
//   Phase 2: W = ws[wb,0]+ws[wb,1]; S16 = W - S1*T; lamEff = -mu*ro*S16;
//            out = cOm + YpT@lamEff (fused-C MFMA), store half-output.
// Lane layout per tile (l = 16q+m): Om master r = Omega[gt+4q+r][m] (C/D);
// YpB e = Yp[m][gt+4q+e] (A-frag); YpA via MFMA transpose (bit-identical);
// P = Yp@Om lands in the B-frag layout needed by the final YpT MFMA.
// d_ws usage: 256 blocks x 256 f32 = 256 KB, written before read each call
// (deterministic, no cross-call state).

typedef float    f32x4 __attribute__((ext_vector_type(4)));
typedef _Float16 f16x4 __attribute__((ext_vector_type(4)));
typedef __fp16   h16x2 __attribute__((ext_vector_type(2)));

#define MUv 1e-3f
#define ROv 1e-3f

__device__ __forceinline__ f16x4 pack4(float a, float b, float c, float d) {
  h16x2 lo = __builtin_amdgcn_cvt_pkrtz(a, b);
  h16x2 hi = __builtin_amdgcn_cvt_pkrtz(c, d);
  union { struct { h16x2 lo, hi; } p; f16x4 v; } u;
  u.p.lo = lo; u.p.hi = hi;
  return u.v;
}

__global__ __launch_bounds__(512) void gd_lagrange_kernel(
    const float* __restrict__ Yp,   // [128][16][1024]
    const float* __restrict__ Uk,   // [128][16][16]
    const float* __restrict__ Lm,   // [128][16][16]
    const float* __restrict__ Om0,  // [128][1024][16]
    const int* __restrict__ nitp,   // [1]
    float* __restrict__ out,        // [128][1024][16]
    float* __restrict__ wsf) {      // [256][256] partials
  constexpr int NT = 4;

  const int bid  = blockIdx.x;
  const int wb   = bid >> 1;        // (w,b) index
  const int hf   = bid & 1;         // G-half
  const int tid  = threadIdx.x;
  const int wv   = tid >> 6;
  const int lane = tid & 63;
  const int q    = (tid >> 4) & 3;
  const int m    = tid & 15;
  const int g0   = hf * 512 + wv * 64;   // wave's 64-row range

  __shared__ float ldsRed[8][256];   // per-wave W partials (b128 slots)

  const float* ypg = Yp + (size_t)wb * 16384;
  const float* omg = Om0 + (size_t)wb * 16384;

  // ---- PHASE 1: issue all global loads (max MLP) ----
  f32x4 rb[NT];
  #pragma unroll
  for (int t = 0; t < NT; ++t)
    rb[t] = *(const f32x4*)&ypg[m * 1024 + g0 + 16 * t + 4 * q];
  f32x4 Om[NT];
  #pragma unroll
  for (int t = 0; t < NT; ++t)
    #pragma unroll
    for (int r = 0; r < 4; ++r)
      Om[t][r] = omg[(g0 + 16 * t + 4 * q + r) * 16 + m];
  f32x4 tgt;   // (Uk@Lambda)[4q+e][m]; Lambda_k diagonal by construction
  {
    const float* uk = Uk + wb * 256;
    float Ld = Lm[wb * 256 + m * 17];
    #pragma unroll
    for (int e = 0; e < 4; ++e)
      tgt[e] = uk[(4 * q + e) * 16 + m] * Ld;
  }

  // ---- static frags ----
  f16x4 Ifrag, ones1;
  #pragma unroll
  for (int e = 0; e < 4; ++e) {
    Ifrag[e] = (4 * q + e == m) ? (_Float16)1.0f : (_Float16)0.0f;
    ones1[e] = (_Float16)1.0f;
  }

  // ---- frags: YpB direct; YpA via MFMA transpose (bit-identical) ----
  f16x4 YpB[NT], YpA[NT];
  #pragma unroll
  for (int t = 0; t < NT; ++t)
    YpB[t] = pack4(rb[t][0], rb[t][1], rb[t][2], rb[t][3]);
  #pragma unroll
  for (int t = 0; t < NT; ++t) {
    f32x4 z = {0.f, 0.f, 0.f, 0.f};
    f32x4 d = __builtin_amdgcn_mfma_f32_16x16x16f16(YpB[t], Ifrag, z, 0, 0, 0);
    YpA[t] = pack4(d[0], d[1], d[2], d[3]);
  }

  // ---- frozen per-element u (row-norm of Om_0, master slots) ----
  f16x4 OmB[NT];
  f32x4 uf[NT];
  #pragma unroll
  for (int t = 0; t < NT; ++t)
    OmB[t] = pack4(Om[t][0], Om[t][1], Om[t][2], Om[t][3]);
  #pragma unroll
  for (int t = 0; t < NT; ++t) {
    f32x4 z = {0.f, 0.f, 0.f, 0.f};
    f16x4 sq = OmB[t] * OmB[t];
    f32x4 d1 = __builtin_amdgcn_mfma_f32_16x16x16f16(sq, Ifrag, z, 0, 0, 0);
    f16x4 t1 = pack4(d1[0], d1[1], d1[2], d1[3]);
    f32x4 n2 = __builtin_amdgcn_mfma_f32_16x16x16f16(t1, ones1, z, 0, 0, 0);
    #pragma unroll
    for (int r = 0; r < 4; ++r)
      uf[t][r] = -MUv * __builtin_amdgcn_rsqf(n2[r]);
  }

  // ---- P0 = Yp@Om_0, Pu = Yp@(SIG*u⊙Om_0) partials (f32 accum) ----
  constexpr float SIG = 4096.f, ISIG = 1.f / 4096.f;
  f32x4 p0a = {0.f, 0.f, 0.f, 0.f}, p0b = {0.f, 0.f, 0.f, 0.f};
  f32x4 pua = {0.f, 0.f, 0.f, 0.f}, pub = {0.f, 0.f, 0.f, 0.f};
  #pragma unroll
  for (int t = 0; t < NT; ++t) {
    f16x4 OmU = pack4(SIG * uf[t][0] * Om[t][0], SIG * uf[t][1] * Om[t][1],
                      SIG * uf[t][2] * Om[t][2], SIG * uf[t][3] * Om[t][3]);
    if (t & 1) {
      p0b = __builtin_amdgcn_mfma_f32_16x16x16f16(YpB[t], OmB[t], p0b, 0, 0, 0);
      pub = __builtin_amdgcn_mfma_f32_16x16x16f16(YpB[t], OmU,    pub, 0, 0, 0);
    } else {
      p0a = __builtin_amdgcn_mfma_f32_16x16x16f16(YpB[t], OmB[t], p0a, 0, 0, 0);
      pua = __builtin_amdgcn_mfma_f32_16x16x16f16(YpB[t], OmU,    pua, 0, 0, 0);
    }
  }

  const int niter = nitp[0];
  const float Nf  = (float)niter;
  const float S1f = 0.5f * Nf * (Nf - 1.f);
  const float S2f = Nf * (Nf - 1.f) * (Nf - 2.f) * (1.f / 6.f);
  f32x4 Wpart = (f32x4)(S1f) * (p0a + p0b) + (f32x4)(S2f * ISIG) * (pua + pub);
  *(f32x4*)&ldsRed[wv][lane * 4] = Wpart;

  // ---- c_N = (1+u)^N (binary pow), fold into Om_0 (stays in regs) ----
  f32x4 cOm[NT];
  #pragma unroll
  for (int t = 0; t < NT; ++t) {
    #pragma unroll
    for (int r = 0; r < 4; ++r) {
      float base = 1.f + uf[t][r];
      float cn = 1.f;
      int n = niter;
      while (n) { if (n & 1) cn *= base; base *= base; n >>= 1; }
      cOm[t][r] = cn * Om[t][r];
    }
  }

  __syncthreads();
  if (wv == 0) {   // block partial -> workspace
    f32x4 s0 = *(const f32x4*)&ldsRed[0][lane * 4];
    #pragma unroll
    for (int w2 = 1; w2 < 8; ++w2)
      s0 += *(const f32x4*)&ldsRed[w2][lane * 4];
    *(f32x4*)&wsf[bid * 256 + lane * 4] = s0;
  }

  cg::this_grid().sync();   // all 256 blocks resident (1/CU)

  // ---- PHASE 2: combine the two half partials, final MFMA, store ----
  f32x4 wA = *(const f32x4*)&wsf[(wb * 2 + 0) * 256 + lane * 4];
  f32x4 wB = *(const f32x4*)&wsf[(wb * 2 + 1) * 256 + lane * 4];
  f32x4 S16 = (wA + wB) - (f32x4)(S1f) * tgt;
  constexpr float KLAM = -(MUv) * (ROv);
  f16x4 lamEff = pack4(KLAM * S16[0], KLAM * S16[1],
                       KLAM * S16[2], KLAM * S16[3]);

  float* og = out + (size_t)wb * 16384;
  #pragma unroll
  for (int t = 0; t < NT; ++t) {
    f32x4 o = __builtin_amdgcn_mfma_f32_16x16x16f16(YpA[t], lamEff, cOm[t], 0, 0, 0);
    #pragma unroll
    for (int r = 0; r < 4; ++r)
      og[(g0 + 16 * t + 4 * q + r) * 16 + m] = o[r];
  }
}

extern "C" void kernel_launch(void* const* d_in, const int* in_sizes, int n_in,
                              void* d_out, int out_size, void* d_ws, size_t ws_size,
                              hipStream_t stream) {
  const float* Yp  = (const float*)d_in[0];
  const float* Uk  = (const float*)d_in[1];
  const float* Lm  = (const float*)d_in[2];
  const float* Om0 = (const float*)d_in[3];
  const int*   nit = (const int*)d_in[4];
  float* outp = (float*)d_out;
  float* wsp  = (float*)d_ws;

  void* args[] = {(void*)&Yp, (void*)&Uk, (void*)&Lm, (void*)&Om0,
                  (void*)&nit, (void*)&outp, (void*)&wsp};
  hipLaunchCooperativeKernel((void*)gd_lagrange_kernel,
                             dim3(256), dim3(512), args, 0, stream);
}

// Round 19
// 14.220 us; speedup vs baseline: 3.5645x; 3.5645x over previous
//
#include <hip/hip_runtime.h>

// GD_lagrange_multi fused kernel for MI355X (gfx950).  Round 19: R17 closed
// form at 4 waves/SIMD (1024-thread blocks) for memory-phase TLP.
//   Om_N = (1+u)^N ⊙ Om_0  -  mu*ro * YpT @ [ S1*(M0 - T) + S2*Mu ]
//   M0 = Yp@Om_0,  Mu = Yp@(u⊙Om_0),  S1 = N(N-1)/2,  S2 = N(N-1)(N-2)/6,
//   u = -mu/||Om_0 row||  (frozen norm; absmax bit-identical since R13).
// One block per (w,b): 16 waves (4/SIMD), wave owns 64 g-rows = 4 tiles
// (16x16x16 f16, f32 accum).  One barrier total.
//
// Lane layout (per tile), lane l = 16q + m:
//   Om[t]  r = Omega[g0+16t+4q+r][j=m]   (C/D layout, f32 master)
//   OmB[t] e = Omega[g0+16t+4q+e][j=m]   (B-frag, k=g)
//   YpB[t] e = Yp[i=m][g0+16t+4q+e]      (A-frag, k=g)
//   YpA[t] e = Yp[s=4q+e][g0+16t+m]      (A-frag, k=s; via MFMA transpose,
//                                         bit-identical to load path)
// P = Yp@Om lands in C/D layout == B-frag layout for the final YpT MFMA.
// u⊙Om scaled by SIG=4096 (exact pow2) for the f16 pack; unscaled in S2.
// Partials: f32x4 b128, lane-contiguous, single write -> barrier -> read.

typedef float    f32x4 __attribute__((ext_vector_type(4)));
typedef _Float16 f16x4 __attribute__((ext_vector_type(4)));
typedef __fp16   h16x2 __attribute__((ext_vector_type(2)));

#define MUv 1e-3f
#define ROv 1e-3f

__device__ __forceinline__ f16x4 pack4(float a, float b, float c, float d) {
  h16x2 lo = __builtin_amdgcn_cvt_pkrtz(a, b);
  h16x2 hi = __builtin_amdgcn_cvt_pkrtz(c, d);
  union { struct { h16x2 lo, hi; } p; f16x4 v; } u;
  u.p.lo = lo; u.p.hi = hi;
  return u.v;
}

__global__ __launch_bounds__(1024) void gd_lagrange_kernel(
    const float* __restrict__ Yp,   // [128][16][1024]
    const float* __restrict__ Uk,   // [128][16][16]
    const float* __restrict__ Lm,   // [128][16][16]
    const float* __restrict__ Om0,  // [128][1024][16]
    const int* __restrict__ nitp,   // [1]
    float* __restrict__ out) {      // [128][1024][16]
  constexpr int NT = 4, NW = 16;

  const int wb   = blockIdx.x;
  const int tid  = threadIdx.x;
  const int wv   = tid >> 6;
  const int lane = tid & 63;
  const int q    = (tid >> 4) & 3;
  const int m    = tid & 15;
  const int g0   = wv * 64;

  __shared__ float ldsRed[NW][256];   // f32x4 partials, lane-contiguous b128

  const float* ypg = Yp + (size_t)wb * 16384;
  const float* omg = Om0 + (size_t)wb * 16384;

  // ---- PHASE 1: issue all global loads (max MLP; 4 waves/SIMD TLP) ----
  f32x4 rb[NT];
  #pragma unroll
  for (int t = 0; t < NT; ++t)
    rb[t] = *(const f32x4*)&ypg[m * 1024 + g0 + 16 * t + 4 * q];
  f32x4 Om[NT];
  #pragma unroll
  for (int t = 0; t < NT; ++t)
    #pragma unroll
    for (int r = 0; r < 4; ++r)
      Om[t][r] = omg[(g0 + 16 * t + 4 * q + r) * 16 + m];
  f32x4 tgt;   // (Uk@Lambda)[4q+e][m]; Lambda_k diagonal by construction
  {
    const float* uk = Uk + wb * 256;
    float Ld = Lm[wb * 256 + m * 17];
    #pragma unroll
    for (int e = 0; e < 4; ++e)
      tgt[e] = uk[(4 * q + e) * 16 + m] * Ld;
  }

  // ---- static frags ----
  f16x4 Ifrag, ones1;
  #pragma unroll
  for (int e = 0; e < 4; ++e) {
    Ifrag[e] = (4 * q + e == m) ? (_Float16)1.0f : (_Float16)0.0f;
    ones1[e] = (_Float16)1.0f;
  }

  // ---- frags: YpB direct; YpA via MFMA transpose (bit-identical) ----
  f16x4 YpB[NT], YpA[NT];
  #pragma unroll
  for (int t = 0; t < NT; ++t)
    YpB[t] = pack4(rb[t][0], rb[t][1], rb[t][2], rb[t][3]);
  #pragma unroll
  for (int t = 0; t < NT; ++t) {
    f32x4 z = {0.f, 0.f, 0.f, 0.f};
    f32x4 d = __builtin_amdgcn_mfma_f32_16x16x16f16(YpB[t], Ifrag, z, 0, 0, 0);
    YpA[t] = pack4(d[0], d[1], d[2], d[3]);
  }

  // ---- frozen per-element u (row-norm of Om_0, master slots) ----
  f16x4 OmB[NT];
  f32x4 uf[NT];
  #pragma unroll
  for (int t = 0; t < NT; ++t)
    OmB[t] = pack4(Om[t][0], Om[t][1], Om[t][2], Om[t][3]);
  #pragma unroll
  for (int t = 0; t < NT; ++t) {
    f32x4 z = {0.f, 0.f, 0.f, 0.f};
    f16x4 sq = OmB[t] * OmB[t];
    f32x4 d1 = __builtin_amdgcn_mfma_f32_16x16x16f16(sq, Ifrag, z, 0, 0, 0);
    f16x4 t1 = pack4(d1[0], d1[1], d1[2], d1[3]);
    f32x4 n2 = __builtin_amdgcn_mfma_f32_16x16x16f16(t1, ones1, z, 0, 0, 0);
    #pragma unroll
    for (int r = 0; r < 4; ++r)
      uf[t][r] = -MUv * __builtin_amdgcn_rsqf(n2[r]);
  }

  // ---- P0 = Yp@Om_0, Pu = Yp@(SIG*u⊙Om_0) partials (f32 accum) ----
  constexpr float SIG = 4096.f, ISIG = 1.f / 4096.f;
  f32x4 p0a = {0.f, 0.f, 0.f, 0.f}, p0b = {0.f, 0.f, 0.f, 0.f};
  f32x4 pua = {0.f, 0.f, 0.f, 0.f}, pub = {0.f, 0.f, 0.f, 0.f};
  #pragma unroll
  for (int t = 0; t < NT; ++t) {
    f16x4 OmU = pack4(SIG * uf[t][0] * Om[t][0], SIG * uf[t][1] * Om[t][1],
                      SIG * uf[t][2] * Om[t][2], SIG * uf[t][3] * Om[t][3]);
    if (t & 1) {
      p0b = __builtin_amdgcn_mfma_f32_16x16x16f16(YpB[t], OmB[t], p0b, 0, 0, 0);
      pub = __builtin_amdgcn_mfma_f32_16x16x16f16(YpB[t], OmU,    pub, 0, 0, 0);
    } else {
      p0a = __builtin_amdgcn_mfma_f32_16x16x16f16(YpB[t], OmB[t], p0a, 0, 0, 0);
      pua = __builtin_amdgcn_mfma_f32_16x16x16f16(YpB[t], OmU,    pua, 0, 0, 0);
    }
  }

  const int niter = nitp[0];
  const float Nf  = (float)niter;
  const float S1f = 0.5f * Nf * (Nf - 1.f);
  const float S2f = Nf * (Nf - 1.f) * (Nf - 2.f) * (1.f / 6.f);
  f32x4 Wpart = (f32x4)(S1f) * (p0a + p0b) + (f32x4)(S2f * ISIG) * (pua + pub);
  *(f32x4*)&ldsRed[wv][lane * 4] = Wpart;

  // ---- c_N = (1+u)^N via binary pow (wave-uniform N), fold into Om_0 ----
  f32x4 cOm[NT];
  #pragma unroll
  for (int t = 0; t < NT; ++t) {
    #pragma unroll
    for (int r = 0; r < 4; ++r) {
      float base = 1.f + uf[t][r];
      float cn = 1.f;
      int n = niter;
      while (n) { if (n & 1) cn *= base; base *= base; n >>= 1; }
      cOm[t][r] = cn * Om[t][r];
    }
  }

  __syncthreads();   // the only barrier

  // ---- S16 = sum_w W_w - S1*T;  lamEff = -mu*ro*S16 (B-frag layout) ----
  f32x4 s0 = {0.f,0.f,0.f,0.f}, s1 = {0.f,0.f,0.f,0.f},
        s2 = {0.f,0.f,0.f,0.f}, s3 = {0.f,0.f,0.f,0.f};
  #pragma unroll
  for (int w2 = 0; w2 < 4; ++w2) {
    s0 += *(const f32x4*)&ldsRed[w2][lane * 4];
    s1 += *(const f32x4*)&ldsRed[w2 + 4][lane * 4];
    s2 += *(const f32x4*)&ldsRed[w2 + 8][lane * 4];
    s3 += *(const f32x4*)&ldsRed[w2 + 12][lane * 4];
  }
  f32x4 S16 = ((s0 + s1) + (s2 + s3)) - (f32x4)(S1f) * tgt;
  constexpr float KLAM = -(MUv) * (ROv);
  f16x4 lamEff = pack4(KLAM * S16[0], KLAM * S16[1],
                       KLAM * S16[2], KLAM * S16[3]);

  // ---- Om_out = cN⊙Om_0 + YpT@lamEff (fused C); store ----
  float* og = out + (size_t)wb * 16384;
  #pragma unroll
  for (int t = 0; t < NT; ++t) {
    f32x4 o = __builtin_amdgcn_mfma_f32_16x16x16f16(YpA[t], lamEff, cOm[t], 0, 0, 0);
    #pragma unroll
    for (int r = 0; r < 4; ++r)
      og[(g0 + 16 * t + 4 * q + r) * 16 + m] = o[r];
  }
}

extern "C" void kernel_launch(void* const* d_in, const int* in_sizes, int n_in,
                              void* d_out, int out_size, void* d_ws, size_t ws_size,
                              hipStream_t stream) {
  const float* Yp  = (const float*)d_in[0];
  const float* Uk  = (const float*)d_in[1];
  const float* Lm  = (const float*)d_in[2];
  const float* Om0 = (const float*)d_in[3];
  const int*   nit = (const int*)d_in[4];
  float* out = (float*)d_out;

  gd_lagrange_kernel<<<dim3(128), dim3(1024), 0, stream>>>(Yp, Uk, Lm, Om0, nit, out);
}